// Round 1
// 3209.443 us; speedup vs baseline: 1.0822x; 1.0822x over previous
//
#include <hip/hip_runtime.h>
#include <hip/hip_fp16.h>

// Encoder: h = normalize_rows(x @ W1^T + b1) * 1.8 ; APPNP K=10, alpha=0.15
// N=100000, E=3200000, IN=512, OUT=256. Output fp32 [N,256].
//
// R1: propagation state in fp16 (y = dinv*z), halving gather traffic.
// R2: GEMM moved to matrix cores (mfma_f32_16x16x32_f16, fp32 accum).
//     - W1 [256][512] is already B-fragment layout [col][k]; convert to fp16
//       once, load B frags straight from global (L2-resident, 256 KB).
//     - Block = 64 rows x 256 cols (full N per block -> A fetched once,
//       FETCH 428 MB -> ~210 MB). A staged fp32->fp16 into LDS.

#define ALPHA 0.15f
#define BETA 0.85f
#define SCALE 1.8f

typedef _Float16 f16x8 __attribute__((ext_vector_type(8)));
typedef float f32x4 __attribute__((ext_vector_type(4)));

// ---------------- convert W1 [256][512] fp32 -> fp16 (same layout) --------
__global__ void convert_w(const float* __restrict__ W1, _Float16* __restrict__ Wh) {
    int i = blockIdx.x * blockDim.x + threadIdx.x;
    if (i < 256 * 512) Wh[i] = (_Float16)W1[i];
}

// ---------------- MFMA GEMM: C[M,256] = A[M,512] * W1^T + bias ------------
// grid.x = ceil(M/64), 256 threads = 4 waves; wave w owns cols [w*64,w*64+64)
__global__ __launch_bounds__(256) void gemm_f16(
    const float* __restrict__ A, const _Float16* __restrict__ Wh,
    const float* __restrict__ bias, float* __restrict__ C, int M) {
    __shared__ _Float16 As[64][72];   // 64 rows x 64 k (fp16), stride 72 halves
    const int tid  = threadIdx.x;
    const int wv   = tid >> 6;
    const int lane = tid & 63;
    const int lc   = lane & 15;       // col-in-tile / row-in-A-frag
    const int lr   = lane >> 4;       // 0..3: k-chunk select / row-quad
    const int m0   = blockIdx.x * 64;
    const int n0w  = wv * 64;

    f32x4 acc[4][4];
#pragma unroll
    for (int i = 0; i < 4; i++)
#pragma unroll
        for (int j = 0; j < 4; j++) {
            acc[i][j][0] = 0.f; acc[i][j][1] = 0.f;
            acc[i][j][2] = 0.f; acc[i][j][3] = 0.f;
        }

    const int srow = tid >> 2;        // 0..63 staging row
    const int sseg = tid & 3;         // 0..3  (16 floats each)
    const bool inb = (m0 + srow) < M;

    for (int k0 = 0; k0 < 512; k0 += 64) {
        // ---- load A tile (fp32), convert, stage to LDS ----
        float4 av0, av1, av2, av3;
        if (inb) {
            const float4* ap = (const float4*)(A + (size_t)(m0 + srow) * 512 + k0 + sseg * 16);
            av0 = ap[0]; av1 = ap[1]; av2 = ap[2]; av3 = ap[3];
        } else {
            av0 = av1 = av2 = av3 = make_float4(0.f, 0.f, 0.f, 0.f);
        }
        if (k0) __syncthreads();
        f16x8 p0, p1;
        p0[0] = (_Float16)av0.x; p0[1] = (_Float16)av0.y;
        p0[2] = (_Float16)av0.z; p0[3] = (_Float16)av0.w;
        p0[4] = (_Float16)av1.x; p0[5] = (_Float16)av1.y;
        p0[6] = (_Float16)av1.z; p0[7] = (_Float16)av1.w;
        p1[0] = (_Float16)av2.x; p1[1] = (_Float16)av2.y;
        p1[2] = (_Float16)av2.z; p1[3] = (_Float16)av2.w;
        p1[4] = (_Float16)av3.x; p1[5] = (_Float16)av3.y;
        p1[6] = (_Float16)av3.z; p1[7] = (_Float16)av3.w;
        _Float16* wp = &As[srow][sseg * 16];
        *(f16x8*)wp = p0;
        *(f16x8*)(wp + 8) = p1;
        __syncthreads();

        // ---- B fragments straight from global (L2-resident 256 KB) ----
        // B[k][n] = W1[n][k]; frag: lane holds B[k0+s*32+lr*8 .. +8)[n0w+nt*16+lc]
        f16x8 bf[2][4];
#pragma unroll
        for (int s = 0; s < 2; ++s)
#pragma unroll
            for (int nt = 0; nt < 4; ++nt)
                bf[s][nt] = *(const f16x8*)(Wh + (size_t)(n0w + nt * 16 + lc) * 512
                                            + k0 + s * 32 + lr * 8);

        // ---- MFMA: 2 k-slices x 4 mt x 4 nt ----
#pragma unroll
        for (int s = 0; s < 2; ++s) {
            f16x8 af[4];
#pragma unroll
            for (int mt = 0; mt < 4; ++mt)
                af[mt] = *(const f16x8*)&As[mt * 16 + lc][s * 32 + lr * 8];
#pragma unroll
            for (int mt = 0; mt < 4; ++mt)
#pragma unroll
                for (int nt = 0; nt < 4; ++nt)
                    acc[mt][nt] = __builtin_amdgcn_mfma_f32_16x16x32_f16(
                        af[mt], bf[s][nt], acc[mt][nt], 0, 0, 0);
        }
    }

    // ---- epilogue: bias + store fp32 ----
    // C/D layout: col = lane&15 (+16*nt), row = (lane>>4)*4 + r (+16*mt)
    float bv[4];
#pragma unroll
    for (int nt = 0; nt < 4; ++nt) bv[nt] = bias[n0w + nt * 16 + lc];
#pragma unroll
    for (int mt = 0; mt < 4; ++mt)
#pragma unroll
        for (int r = 0; r < 4; ++r) {
            int m = m0 + mt * 16 + lr * 4 + r;
            if (m < M) {
                float* cp = C + (size_t)m * 256 + n0w + lc;
#pragma unroll
                for (int nt = 0; nt < 4; ++nt)
                    cp[nt * 16] = acc[mt][nt][r] + bv[nt];
            }
        }
}

// ------ row L2-normalize * 1.8; emit fp16 h16 (alpha term) + y0 = h*dinv --
__global__ __launch_bounds__(256) void normalize_kernel(
    const float* __restrict__ h, const float* __restrict__ dinv,
    __half* __restrict__ h16, __half* __restrict__ y0, int N) {
    int n = blockIdx.x;
    if (n >= N) return;
    int t = threadIdx.x;
    float v = h[(size_t)n * 256 + t];
    float ss = v * v;
#pragma unroll
    for (int off = 32; off > 0; off >>= 1) ss += __shfl_down(ss, off, 64);
    __shared__ float wsum[4];
    int w = t >> 6, lane = t & 63;
    if (lane == 0) wsum[w] = ss;
    __syncthreads();
    float tot = wsum[0] + wsum[1] + wsum[2] + wsum[3];
    float nrm = sqrtf(tot);
    float s = SCALE / fmaxf(nrm, 1e-12f);
    float hv = v * s;
    h16[(size_t)n * 256 + t] = __float2half(hv);
    y0[(size_t)n * 256 + t] = __float2half(hv * dinv[n]);
}

// ---------------- degree / CSR build --------------------------------------
__global__ void init_counts(int* __restrict__ counts, int N) {
    int i = blockIdx.x * blockDim.x + threadIdx.x;
    if (i < N) counts[i] = 1;   // self-loop
}

__global__ void count_kernel(const int* __restrict__ dst, int* __restrict__ counts, int E) {
    int i = blockIdx.x * blockDim.x + threadIdx.x;
    if (i < E) atomicAdd(&counts[dst[i]], 1);
}

__global__ void dinv_kernel(const int* __restrict__ counts, float* __restrict__ dinv, int N) {
    int i = blockIdx.x * blockDim.x + threadIdx.x;
    if (i < N) dinv[i] = rsqrtf((float)counts[i]);
}

__global__ __launch_bounds__(256) void scan_phase1(
    const int* __restrict__ counts, int* __restrict__ offsets,
    int* __restrict__ blocksums, int N) {
    __shared__ int sdata[256];
    int b = blockIdx.x;
    int base = b * 1024;
    int t = threadIdx.x;
    int v[4];
    int idx0 = base + t * 4;
    int sum = 0;
#pragma unroll
    for (int j = 0; j < 4; j++) {
        int i = idx0 + j;
        v[j] = (i < N) ? counts[i] : 0;
        sum += v[j];
    }
    sdata[t] = sum;
    __syncthreads();
    for (int off = 1; off < 256; off <<= 1) {
        int x = (t >= off) ? sdata[t - off] : 0;
        __syncthreads();
        sdata[t] += x;
        __syncthreads();
    }
    int incl = sdata[t];
    int excl = incl - sum;
    if (t == 255) blocksums[b] = incl;
    int run = excl;
#pragma unroll
    for (int j = 0; j < 4; j++) {
        int i = idx0 + j;
        if (i < N) offsets[i] = run;
        run += v[j];
    }
}

__global__ __launch_bounds__(128) void scan_phase2(int* __restrict__ blocksums, int nb) {
    __shared__ int s[128];
    int t = threadIdx.x;
    int v = (t < nb) ? blocksums[t] : 0;
    s[t] = v;
    __syncthreads();
    for (int off = 1; off < 128; off <<= 1) {
        int x = (t >= off) ? s[t - off] : 0;
        __syncthreads();
        s[t] += x;
        __syncthreads();
    }
    if (t < nb) blocksums[t] = s[t] - v;   // exclusive
}

__global__ void scan_phase3(int* __restrict__ offsets, const int* __restrict__ blocksums,
                            int* __restrict__ cursor, int N, int total) {
    int i = blockIdx.x * blockDim.x + threadIdx.x;
    if (i < N) {
        int o = offsets[i] + blocksums[i >> 10];
        offsets[i] = o;
        cursor[i] = o;
    }
    if (i == N) offsets[N] = total;
}

__global__ void fill_kernel(const int* __restrict__ src, const int* __restrict__ dst,
                            int* __restrict__ cursor, int* __restrict__ col, int E, int N) {
    int i = blockIdx.x * blockDim.x + threadIdx.x;
    int tot = E + N;
    if (i >= tot) return;
    int s, d;
    if (i < E) { s = src[i]; d = dst[i]; }
    else       { s = d = i - E; }
    int p = atomicAdd(&cursor[d], 1);
    col[p] = s;
}

// ---------------- pull-SpMM over fp16 state: one wave per dst row ---------
__device__ __forceinline__ void acc_half4(float4& a, float2 r) {
    union { float2 f; __half2 h[2]; } u;
    u.f = r;
    float2 lo = __half22float2(u.h[0]);
    float2 hi = __half22float2(u.h[1]);
    a.x += lo.x; a.y += lo.y; a.z += hi.x; a.w += hi.y;
}

template <bool FINAL>
__global__ __launch_bounds__(256) void spmm_kernel(
    const __half* __restrict__ yin, const __half* __restrict__ h16,
    const int* __restrict__ offs, const int* __restrict__ col,
    const float* __restrict__ dinv, void* __restrict__ outp, int N) {
    int gw = blockIdx.x * 4 + (threadIdx.x >> 6);
    if (gw >= N) return;
    int lane = threadIdx.x & 63;
    int beg = offs[gw], end = offs[gw + 1];

    float4 a0 = make_float4(0.f, 0.f, 0.f, 0.f);
    float4 a1 = make_float4(0.f, 0.f, 0.f, 0.f);
    float4 a2 = make_float4(0.f, 0.f, 0.f, 0.f);
    float4 a3 = make_float4(0.f, 0.f, 0.f, 0.f);

    int e = beg;
    for (; e + 3 < end; e += 4) {
        int s0 = __builtin_nontemporal_load(col + e);
        int s1 = __builtin_nontemporal_load(col + e + 1);
        int s2 = __builtin_nontemporal_load(col + e + 2);
        int s3 = __builtin_nontemporal_load(col + e + 3);
        float2 r0 = ((const float2*)(yin + (size_t)s0 * 256))[lane];
        float2 r1 = ((const float2*)(yin + (size_t)s1 * 256))[lane];
        float2 r2 = ((const float2*)(yin + (size_t)s2 * 256))[lane];
        float2 r3 = ((const float2*)(yin + (size_t)s3 * 256))[lane];
        acc_half4(a0, r0); acc_half4(a1, r1); acc_half4(a2, r2); acc_half4(a3, r3);
    }
    for (; e < end; ++e) {
        int s0 = __builtin_nontemporal_load(col + e);
        float2 r0 = ((const float2*)(yin + (size_t)s0 * 256))[lane];
        acc_half4(a0, r0);
    }

    float dg = dinv[gw];
    float wd = BETA * dg;

    // alpha * h0 term (fp16, streaming)
    const float* hp = (const float*)(h16 + (size_t)gw * 256) + lane * 2;
    float hx = __builtin_nontemporal_load(hp);
    float hy = __builtin_nontemporal_load(hp + 1);
    float4 hh;
    {
        union { float f; __half2 h; } ux, uy;
        ux.f = hx; uy.f = hy;
        float2 lo = __half22float2(ux.h);
        float2 hi = __half22float2(uy.h);
        hh.x = lo.x; hh.y = lo.y; hh.z = hi.x; hh.w = hi.y;
    }

    float4 o;
    o.x = wd * (a0.x + a1.x + a2.x + a3.x) + ALPHA * hh.x;
    o.y = wd * (a0.y + a1.y + a2.y + a3.y) + ALPHA * hh.y;
    o.z = wd * (a0.z + a1.z + a2.z + a3.z) + ALPHA * hh.z;
    o.w = wd * (a0.w + a1.w + a2.w + a3.w) + ALPHA * hh.w;

    if (FINAL) {
        float* op = (float*)outp + (size_t)gw * 256 + lane * 4;
        __builtin_nontemporal_store(o.x, op);
        __builtin_nontemporal_store(o.y, op + 1);
        __builtin_nontemporal_store(o.z, op + 2);
        __builtin_nontemporal_store(o.w, op + 3);
    } else {
        // store y = dinv[d] * z for the next iteration's gathers
        __half2 p0 = __floats2half2_rn(o.x * dg, o.y * dg);
        __half2 p1 = __floats2half2_rn(o.z * dg, o.w * dg);
        union { float f; __half2 h; } u0, u1;
        u0.h = p0; u1.h = p1;
        float* op = (float*)((__half*)outp + (size_t)gw * 256) + lane * 2;
        __builtin_nontemporal_store(u0.f, op);
        __builtin_nontemporal_store(u1.f, op + 1);
    }
}

extern "C" void kernel_launch(void* const* d_in, const int* in_sizes, int n_in,
                              void* d_out, int out_size, void* d_ws, size_t ws_size,
                              hipStream_t stream) {
    const float* x  = (const float*)d_in[0];
    const int* ei   = (const int*)d_in[1];
    const float* W1 = (const float*)d_in[2];
    const float* b1 = (const float*)d_in[3];
    float* out = (float*)d_out;

    const int N = in_sizes[0] / 512;           // 100000
    const int E = in_sizes[1] / 2;             // 3200000
    const int* src = ei;
    const int* dst = ei + E;
    const int NNZ = E + N;

    // workspace carve-up; h0 (fp32) region is reused as yA (fp16)
    char* w = (char*)d_ws;
    float* h0 = (float*)w;      w += (size_t)N * 256 * 4;      // fp32 GEMM out / later yA
    __half* h16 = (__half*)w;   w += (size_t)N * 256 * 2;      // alpha term
    __half* y0 = (__half*)w;    w += (size_t)N * 256 * 2;      // initial state
    __half* yB = (__half*)w;    w += (size_t)N * 256 * 2;      // ping-pong B
    _Float16* Wh = (_Float16*)w; w += (size_t)256 * 512 * 2;   // fp16 W1 (B frags)
    float* dinv = (float*)w;    w += (size_t)N * 4;
    int* counts = (int*)w;      w += (size_t)N * 4;            // reused as cursor
    int* offsets = (int*)w;     w += (size_t)(N + 64) * 4;
    int* blocksums = (int*)w;   w += 128 * 4;
    int* col = (int*)w;         w += (size_t)NNZ * 4;
    __half* yA = (__half*)h0;

    // degrees (incl self-loop) + dinv — needed by normalize
    init_counts<<<(N + 255) / 256, 256, 0, stream>>>(counts, N);
    count_kernel<<<(E + 255) / 256, 256, 0, stream>>>(dst, counts, E);
    dinv_kernel<<<(N + 255) / 256, 256, 0, stream>>>(counts, dinv, N);
    // linear1 (fp16 MFMA)
    convert_w<<<(256 * 512 + 255) / 256, 256, 0, stream>>>(W1, Wh);
    gemm_f16<<<(N + 63) / 64, 256, 0, stream>>>(x, Wh, b1, h0, N);
    // normalize -> h16, y0 (h0 fp32 dead after this; region becomes yA)
    normalize_kernel<<<N, 256, 0, stream>>>(h0, dinv, h16, y0, N);
    // CSR
    int nb = (N + 1023) / 1024;
    scan_phase1<<<nb, 256, 0, stream>>>(counts, offsets, blocksums, N);
    scan_phase2<<<1, 128, 0, stream>>>(blocksums, nb);
    scan_phase3<<<(N + 256) / 256, 256, 0, stream>>>(offsets, blocksums, counts, N, NNZ);
    fill_kernel<<<(NNZ + 255) / 256, 256, 0, stream>>>(src, dst, counts, col, E, N);
    // APPNP: 9 fp16->fp16 steps + final fp16->fp32 into d_out
    int nblk = (N + 3) / 4;
    const __half* cur = y0;
    for (int it = 0; it < 9; ++it) {
        __half* nxt = (it & 1) ? yB : yA;
        spmm_kernel<false><<<nblk, 256, 0, stream>>>(cur, h16, offsets, col, dinv,
                                                     (void*)nxt, N);
        cur = nxt;
    }
    spmm_kernel<true><<<nblk, 256, 0, stream>>>(cur, h16, offsets, col, dinv,
                                                (void*)out, N);
}

// Round 2
// 3165.195 us; speedup vs baseline: 1.0973x; 1.0140x over previous
//
#include <hip/hip_runtime.h>
#include <hip/hip_fp16.h>

// Encoder: h = normalize_rows(x @ W1^T + b1) * 1.8 ; APPNP K=10, alpha=0.15
// N=100000, E=3200000, IN=512, OUT=256. Output fp32 [N,256].
//
// R1: propagation state in fp16 (y = dinv*z), halving gather traffic.
// R2: GEMM on matrix cores (mfma_f32_16x16x32_f16, fp32 accum).
// R3: XCD-local CSR build. fill_kernel's random 4B col scatter caused
//     ~200 MB of partial-line L2 writebacks (290 us, top dispatch).
//     Blocks grouped by (blockIdx&7) == XCD round-robin slot; each group
//     only processes dst in its N/8 range -> cursor atomics hit a 50 KB
//     window and col writes a 1.65 MB window, both L2-resident, lines
//     fully filled before the end-of-kernel flush (~13 MB writeback).

#define ALPHA 0.15f
#define BETA 0.85f
#define SCALE 1.8f

typedef _Float16 f16x8 __attribute__((ext_vector_type(8)));
typedef float f32x4 __attribute__((ext_vector_type(4)));

// ---------------- convert W1 [256][512] fp32 -> fp16 (same layout) --------
__global__ void convert_w(const float* __restrict__ W1, _Float16* __restrict__ Wh) {
    int i = blockIdx.x * blockDim.x + threadIdx.x;
    if (i < 256 * 512) Wh[i] = (_Float16)W1[i];
}

// ---------------- MFMA GEMM: C[M,256] = A[M,512] * W1^T + bias ------------
// grid.x = ceil(M/64), 256 threads = 4 waves; wave w owns cols [w*64,w*64+64)
__global__ __launch_bounds__(256) void gemm_f16(
    const float* __restrict__ A, const _Float16* __restrict__ Wh,
    const float* __restrict__ bias, float* __restrict__ C, int M) {
    __shared__ _Float16 As[64][72];   // 64 rows x 64 k (fp16), stride 72 halves
    const int tid  = threadIdx.x;
    const int wv   = tid >> 6;
    const int lane = tid & 63;
    const int lc   = lane & 15;       // col-in-tile / row-in-A-frag
    const int lr   = lane >> 4;       // 0..3: k-chunk select / row-quad
    const int m0   = blockIdx.x * 64;
    const int n0w  = wv * 64;

    f32x4 acc[4][4];
#pragma unroll
    for (int i = 0; i < 4; i++)
#pragma unroll
        for (int j = 0; j < 4; j++) {
            acc[i][j][0] = 0.f; acc[i][j][1] = 0.f;
            acc[i][j][2] = 0.f; acc[i][j][3] = 0.f;
        }

    const int srow = tid >> 2;        // 0..63 staging row
    const int sseg = tid & 3;         // 0..3  (16 floats each)
    const bool inb = (m0 + srow) < M;

    for (int k0 = 0; k0 < 512; k0 += 64) {
        // ---- load A tile (fp32), convert, stage to LDS ----
        float4 av0, av1, av2, av3;
        if (inb) {
            const float4* ap = (const float4*)(A + (size_t)(m0 + srow) * 512 + k0 + sseg * 16);
            av0 = ap[0]; av1 = ap[1]; av2 = ap[2]; av3 = ap[3];
        } else {
            av0 = av1 = av2 = av3 = make_float4(0.f, 0.f, 0.f, 0.f);
        }
        if (k0) __syncthreads();
        f16x8 p0, p1;
        p0[0] = (_Float16)av0.x; p0[1] = (_Float16)av0.y;
        p0[2] = (_Float16)av0.z; p0[3] = (_Float16)av0.w;
        p0[4] = (_Float16)av1.x; p0[5] = (_Float16)av1.y;
        p0[6] = (_Float16)av1.z; p0[7] = (_Float16)av1.w;
        p1[0] = (_Float16)av2.x; p1[1] = (_Float16)av2.y;
        p1[2] = (_Float16)av2.z; p1[3] = (_Float16)av2.w;
        p1[4] = (_Float16)av3.x; p1[5] = (_Float16)av3.y;
        p1[6] = (_Float16)av3.z; p1[7] = (_Float16)av3.w;
        _Float16* wp = &As[srow][sseg * 16];
        *(f16x8*)wp = p0;
        *(f16x8*)(wp + 8) = p1;
        __syncthreads();

        // ---- B fragments straight from global (L2-resident 256 KB) ----
        f16x8 bf[2][4];
#pragma unroll
        for (int s = 0; s < 2; ++s)
#pragma unroll
            for (int nt = 0; nt < 4; ++nt)
                bf[s][nt] = *(const f16x8*)(Wh + (size_t)(n0w + nt * 16 + lc) * 512
                                            + k0 + s * 32 + lr * 8);

        // ---- MFMA: 2 k-slices x 4 mt x 4 nt ----
#pragma unroll
        for (int s = 0; s < 2; ++s) {
            f16x8 af[4];
#pragma unroll
            for (int mt = 0; mt < 4; ++mt)
                af[mt] = *(const f16x8*)&As[mt * 16 + lc][s * 32 + lr * 8];
#pragma unroll
            for (int mt = 0; mt < 4; ++mt)
#pragma unroll
                for (int nt = 0; nt < 4; ++nt)
                    acc[mt][nt] = __builtin_amdgcn_mfma_f32_16x16x32_f16(
                        af[mt], bf[s][nt], acc[mt][nt], 0, 0, 0);
        }
    }

    // ---- epilogue: bias + store fp32 ----
    float bv[4];
#pragma unroll
    for (int nt = 0; nt < 4; ++nt) bv[nt] = bias[n0w + nt * 16 + lc];
#pragma unroll
    for (int mt = 0; mt < 4; ++mt)
#pragma unroll
        for (int r = 0; r < 4; ++r) {
            int m = m0 + mt * 16 + lr * 4 + r;
            if (m < M) {
                float* cp = C + (size_t)m * 256 + n0w + lc;
#pragma unroll
                for (int nt = 0; nt < 4; ++nt)
                    cp[nt * 16] = acc[mt][nt][r] + bv[nt];
            }
        }
}

// ------ row L2-normalize * 1.8; emit fp16 h16 (alpha term) + y0 = h*dinv --
__global__ __launch_bounds__(256) void normalize_kernel(
    const float* __restrict__ h, const float* __restrict__ dinv,
    __half* __restrict__ h16, __half* __restrict__ y0, int N) {
    int n = blockIdx.x;
    if (n >= N) return;
    int t = threadIdx.x;
    float v = h[(size_t)n * 256 + t];
    float ss = v * v;
#pragma unroll
    for (int off = 32; off > 0; off >>= 1) ss += __shfl_down(ss, off, 64);
    __shared__ float wsum[4];
    int w = t >> 6, lane = t & 63;
    if (lane == 0) wsum[w] = ss;
    __syncthreads();
    float tot = wsum[0] + wsum[1] + wsum[2] + wsum[3];
    float nrm = sqrtf(tot);
    float s = SCALE / fmaxf(nrm, 1e-12f);
    float hv = v * s;
    h16[(size_t)n * 256 + t] = __float2half(hv);
    y0[(size_t)n * 256 + t] = __float2half(hv * dinv[n]);
}

// ---------------- degree / CSR build (XCD-local scatter) ------------------
__global__ void init_counts(int* __restrict__ counts, int N) {
    int i = blockIdx.x * blockDim.x + threadIdx.x;
    if (i < N) counts[i] = 1;   // self-loop
}

// blocks grouped by x = blockIdx&7 (round-robin XCD slot); group x only
// processes dst in [x*N/8,(x+1)*N/8). Each (x, chunk) pair owned by exactly
// one block -> every edge processed exactly once regardless of HW mapping.
__global__ __launch_bounds__(256) void count_xcd(
    const int* __restrict__ dst, int* __restrict__ counts, int E, int N) {
    const int b = blockIdx.x, x = b & 7, c = b >> 3;
    const int NC = gridDim.x >> 3;
    const int lo = (int)(((long long)x * N) >> 3);
    const int hi = (int)(((long long)(x + 1) * N) >> 3);
    const int csz = (((E + NC - 1) / NC) + 3) & ~3;
    const int e0 = c * csz;
    const int e1 = min(e0 + csz, E);
    const int rem = (e1 > e0) ? (e1 - e0) : 0;
    const int t = threadIdx.x;
    const int nvec = ((E & 3) == 0) ? (rem >> 2) : 0;
    for (int i = t; i < nvec; i += 256) {
        const int e = e0 + (i << 2);
        int4 d4 = *(const int4*)(dst + e);
        if (d4.x >= lo && d4.x < hi) atomicAdd(&counts[d4.x], 1);
        if (d4.y >= lo && d4.y < hi) atomicAdd(&counts[d4.y], 1);
        if (d4.z >= lo && d4.z < hi) atomicAdd(&counts[d4.z], 1);
        if (d4.w >= lo && d4.w < hi) atomicAdd(&counts[d4.w], 1);
    }
    for (int e = e0 + (nvec << 2) + t; e < e1; e += 256) {
        int d = dst[e];
        if (d >= lo && d < hi) atomicAdd(&counts[d], 1);
    }
}

__global__ void dinv_kernel(const int* __restrict__ counts, float* __restrict__ dinv, int N) {
    int i = blockIdx.x * blockDim.x + threadIdx.x;
    if (i < N) dinv[i] = rsqrtf((float)counts[i]);
}

__global__ __launch_bounds__(256) void scan_phase1(
    const int* __restrict__ counts, int* __restrict__ offsets,
    int* __restrict__ blocksums, int N) {
    __shared__ int sdata[256];
    int b = blockIdx.x;
    int base = b * 1024;
    int t = threadIdx.x;
    int v[4];
    int idx0 = base + t * 4;
    int sum = 0;
#pragma unroll
    for (int j = 0; j < 4; j++) {
        int i = idx0 + j;
        v[j] = (i < N) ? counts[i] : 0;
        sum += v[j];
    }
    sdata[t] = sum;
    __syncthreads();
    for (int off = 1; off < 256; off <<= 1) {
        int x = (t >= off) ? sdata[t - off] : 0;
        __syncthreads();
        sdata[t] += x;
        __syncthreads();
    }
    int incl = sdata[t];
    int excl = incl - sum;
    if (t == 255) blocksums[b] = incl;
    int run = excl;
#pragma unroll
    for (int j = 0; j < 4; j++) {
        int i = idx0 + j;
        if (i < N) offsets[i] = run;
        run += v[j];
    }
}

__global__ __launch_bounds__(128) void scan_phase2(int* __restrict__ blocksums, int nb) {
    __shared__ int s[128];
    int t = threadIdx.x;
    int v = (t < nb) ? blocksums[t] : 0;
    s[t] = v;
    __syncthreads();
    for (int off = 1; off < 128; off <<= 1) {
        int x = (t >= off) ? s[t - off] : 0;
        __syncthreads();
        s[t] += x;
        __syncthreads();
    }
    if (t < nb) blocksums[t] = s[t] - v;   // exclusive
}

__global__ void scan_phase3(int* __restrict__ offsets, const int* __restrict__ blocksums,
                            int* __restrict__ cursor, int N, int total) {
    int i = blockIdx.x * blockDim.x + threadIdx.x;
    if (i < N) {
        int o = offsets[i] + blocksums[i >> 10];
        offsets[i] = o;
        cursor[i] = o;
    }
    if (i == N) offsets[N] = total;
}

__global__ __launch_bounds__(256) void fill_xcd(
    const int* __restrict__ src, const int* __restrict__ dst,
    int* __restrict__ cursor, int* __restrict__ col, int E, int N) {
    const int b = blockIdx.x, x = b & 7, c = b >> 3;
    const int NC = gridDim.x >> 3;
    const int lo = (int)(((long long)x * N) >> 3);
    const int hi = (int)(((long long)(x + 1) * N) >> 3);
    const int csz = (((E + NC - 1) / NC) + 3) & ~3;
    const int e0 = c * csz;
    const int e1 = min(e0 + csz, E);
    const int rem = (e1 > e0) ? (e1 - e0) : 0;
    const int t = threadIdx.x;
    const int nvec = ((E & 3) == 0) ? (rem >> 2) : 0;
    for (int i = t; i < nvec; i += 256) {
        const int e = e0 + (i << 2);
        int4 d4 = *(const int4*)(dst + e);
        if (d4.x >= lo && d4.x < hi) { int p = atomicAdd(&cursor[d4.x], 1); col[p] = src[e]; }
        if (d4.y >= lo && d4.y < hi) { int p = atomicAdd(&cursor[d4.y], 1); col[p] = src[e + 1]; }
        if (d4.z >= lo && d4.z < hi) { int p = atomicAdd(&cursor[d4.z], 1); col[p] = src[e + 2]; }
        if (d4.w >= lo && d4.w < hi) { int p = atomicAdd(&cursor[d4.w], 1); col[p] = src[e + 3]; }
    }
    for (int e = e0 + (nvec << 2) + t; e < e1; e += 256) {
        int d = dst[e];
        if (d >= lo && d < hi) { int p = atomicAdd(&cursor[d], 1); col[p] = src[e]; }
    }
    // self-loops: once per dst-range, done by the c==0 block of each group
    if (c == 0) {
        for (int n = lo + t; n < hi; n += 256) {
            int p = atomicAdd(&cursor[n], 1);
            col[p] = n;
        }
    }
}

// ---------------- pull-SpMM over fp16 state: one wave per dst row ---------
__device__ __forceinline__ void acc_half4(float4& a, float2 r) {
    union { float2 f; __half2 h[2]; } u;
    u.f = r;
    float2 lo = __half22float2(u.h[0]);
    float2 hi = __half22float2(u.h[1]);
    a.x += lo.x; a.y += lo.y; a.z += hi.x; a.w += hi.y;
}

template <bool FINAL>
__global__ __launch_bounds__(256) void spmm_kernel(
    const __half* __restrict__ yin, const __half* __restrict__ h16,
    const int* __restrict__ offs, const int* __restrict__ col,
    const float* __restrict__ dinv, void* __restrict__ outp, int N) {
    int gw = blockIdx.x * 4 + (threadIdx.x >> 6);
    if (gw >= N) return;
    int lane = threadIdx.x & 63;
    int beg = offs[gw], end = offs[gw + 1];

    float4 a0 = make_float4(0.f, 0.f, 0.f, 0.f);
    float4 a1 = make_float4(0.f, 0.f, 0.f, 0.f);
    float4 a2 = make_float4(0.f, 0.f, 0.f, 0.f);
    float4 a3 = make_float4(0.f, 0.f, 0.f, 0.f);

    int e = beg;
    for (; e + 3 < end; e += 4) {
        int s0 = __builtin_nontemporal_load(col + e);
        int s1 = __builtin_nontemporal_load(col + e + 1);
        int s2 = __builtin_nontemporal_load(col + e + 2);
        int s3 = __builtin_nontemporal_load(col + e + 3);
        float2 r0 = ((const float2*)(yin + (size_t)s0 * 256))[lane];
        float2 r1 = ((const float2*)(yin + (size_t)s1 * 256))[lane];
        float2 r2 = ((const float2*)(yin + (size_t)s2 * 256))[lane];
        float2 r3 = ((const float2*)(yin + (size_t)s3 * 256))[lane];
        acc_half4(a0, r0); acc_half4(a1, r1); acc_half4(a2, r2); acc_half4(a3, r3);
    }
    for (; e < end; ++e) {
        int s0 = __builtin_nontemporal_load(col + e);
        float2 r0 = ((const float2*)(yin + (size_t)s0 * 256))[lane];
        acc_half4(a0, r0);
    }

    float dg = dinv[gw];
    float wd = BETA * dg;

    // alpha * h0 term (fp16, streaming)
    const float* hp = (const float*)(h16 + (size_t)gw * 256) + lane * 2;
    float hx = __builtin_nontemporal_load(hp);
    float hy = __builtin_nontemporal_load(hp + 1);
    float4 hh;
    {
        union { float f; __half2 h; } ux, uy;
        ux.f = hx; uy.f = hy;
        float2 lo = __half22float2(ux.h);
        float2 hi = __half22float2(uy.h);
        hh.x = lo.x; hh.y = lo.y; hh.z = hi.x; hh.w = hi.y;
    }

    float4 o;
    o.x = wd * (a0.x + a1.x + a2.x + a3.x) + ALPHA * hh.x;
    o.y = wd * (a0.y + a1.y + a2.y + a3.y) + ALPHA * hh.y;
    o.z = wd * (a0.z + a1.z + a2.z + a3.z) + ALPHA * hh.z;
    o.w = wd * (a0.w + a1.w + a2.w + a3.w) + ALPHA * hh.w;

    if (FINAL) {
        float* op = (float*)outp + (size_t)gw * 256 + lane * 4;
        __builtin_nontemporal_store(o.x, op);
        __builtin_nontemporal_store(o.y, op + 1);
        __builtin_nontemporal_store(o.z, op + 2);
        __builtin_nontemporal_store(o.w, op + 3);
    } else {
        // store y = dinv[d] * z for the next iteration's gathers
        __half2 p0 = __floats2half2_rn(o.x * dg, o.y * dg);
        __half2 p1 = __floats2half2_rn(o.z * dg, o.w * dg);
        union { float f; __half2 h; } u0, u1;
        u0.h = p0; u1.h = p1;
        float* op = (float*)((__half*)outp + (size_t)gw * 256) + lane * 2;
        __builtin_nontemporal_store(u0.f, op);
        __builtin_nontemporal_store(u1.f, op + 1);
    }
}

extern "C" void kernel_launch(void* const* d_in, const int* in_sizes, int n_in,
                              void* d_out, int out_size, void* d_ws, size_t ws_size,
                              hipStream_t stream) {
    const float* x  = (const float*)d_in[0];
    const int* ei   = (const int*)d_in[1];
    const float* W1 = (const float*)d_in[2];
    const float* b1 = (const float*)d_in[3];
    float* out = (float*)d_out;

    const int N = in_sizes[0] / 512;           // 100000
    const int E = in_sizes[1] / 2;             // 3200000
    const int* src = ei;
    const int* dst = ei + E;
    const int NNZ = E + N;

    // workspace carve-up; h0 (fp32) region is reused as yA (fp16)
    char* w = (char*)d_ws;
    float* h0 = (float*)w;      w += (size_t)N * 256 * 4;      // fp32 GEMM out / later yA
    __half* h16 = (__half*)w;   w += (size_t)N * 256 * 2;      // alpha term
    __half* y0 = (__half*)w;    w += (size_t)N * 256 * 2;      // initial state
    __half* yB = (__half*)w;    w += (size_t)N * 256 * 2;      // ping-pong B
    _Float16* Wh = (_Float16*)w; w += (size_t)256 * 512 * 2;   // fp16 W1 (B frags)
    float* dinv = (float*)w;    w += (size_t)N * 4;
    int* counts = (int*)w;      w += (size_t)N * 4;            // reused as cursor
    int* offsets = (int*)w;     w += (size_t)(N + 64) * 4;
    int* blocksums = (int*)w;   w += 128 * 4;
    int* col = (int*)w;         w += (size_t)NNZ * 4;
    __half* yA = (__half*)h0;

    // degrees (incl self-loop) + dinv — needed by normalize
    init_counts<<<(N + 255) / 256, 256, 0, stream>>>(counts, N);
    count_xcd<<<512, 256, 0, stream>>>(dst, counts, E, N);
    dinv_kernel<<<(N + 255) / 256, 256, 0, stream>>>(counts, dinv, N);
    // linear1 (fp16 MFMA)
    convert_w<<<(256 * 512 + 255) / 256, 256, 0, stream>>>(W1, Wh);
    gemm_f16<<<(N + 63) / 64, 256, 0, stream>>>(x, Wh, b1, h0, N);
    // normalize -> h16, y0 (h0 fp32 dead after this; region becomes yA)
    normalize_kernel<<<N, 256, 0, stream>>>(h0, dinv, h16, y0, N);
    // CSR
    int nb = (N + 1023) / 1024;
    scan_phase1<<<nb, 256, 0, stream>>>(counts, offsets, blocksums, N);
    scan_phase2<<<1, 128, 0, stream>>>(blocksums, nb);
    scan_phase3<<<(N + 256) / 256, 256, 0, stream>>>(offsets, blocksums, counts, N, NNZ);
    fill_xcd<<<512, 256, 0, stream>>>(src, dst, counts, col, E, N);
    // APPNP: 9 fp16->fp16 steps + final fp16->fp32 into d_out
    int nblk = (N + 3) / 4;
    const __half* cur = y0;
    for (int it = 0; it < 9; ++it) {
        __half* nxt = (it & 1) ? yB : yA;
        spmm_kernel<false><<<nblk, 256, 0, stream>>>(cur, h16, offsets, col, dinv,
                                                     (void*)nxt, N);
        cur = nxt;
    }
    spmm_kernel<true><<<nblk, 256, 0, stream>>>(cur, h16, offsets, col, dinv,
                                                (void*)out, N);
}

// Round 3
// 3004.566 us; speedup vs baseline: 1.1560x; 1.0535x over previous
//
#include <hip/hip_runtime.h>
#include <hip/hip_fp16.h>

// Encoder: h = normalize_rows(x @ W1^T + b1) * 1.8 ; APPNP K=10, alpha=0.15
// N=100000, E=3200000, IN=512, OUT=256. Output fp32 [N,256].
//
// R1: propagation state in fp16 (y = dinv*z), halving gather traffic.
// R2: GEMM on matrix cores (mfma_f32_16x16x32_f16, fp32 accum).
// R3: XCD-local CSR build (fill/count scatter made L2-local).
// R4: SpMM cache policy + MLP. The per-iteration working set (y_in, y_out,
//     h16, col ~= 167 MB) fits the 256 MB Infinity Cache, but nt hints
//     (evict-first) on col/h16 loads and y stores defeated it ->
//     846 MB HBM fetch/iter. Remove all nt except the final fp32 output
//     store; deepen to 8 row-gathers in flight per wave (8 accumulators).

#define ALPHA 0.15f
#define BETA 0.85f
#define SCALE 1.8f

typedef _Float16 f16x8 __attribute__((ext_vector_type(8)));
typedef float f32x4 __attribute__((ext_vector_type(4)));

// ---------------- convert W1 [256][512] fp32 -> fp16 (same layout) --------
__global__ void convert_w(const float* __restrict__ W1, _Float16* __restrict__ Wh) {
    int i = blockIdx.x * blockDim.x + threadIdx.x;
    if (i < 256 * 512) Wh[i] = (_Float16)W1[i];
}

// ---------------- MFMA GEMM: C[M,256] = A[M,512] * W1^T + bias ------------
__global__ __launch_bounds__(256) void gemm_f16(
    const float* __restrict__ A, const _Float16* __restrict__ Wh,
    const float* __restrict__ bias, float* __restrict__ C, int M) {
    __shared__ _Float16 As[64][72];   // 64 rows x 64 k (fp16), stride 72 halves
    const int tid  = threadIdx.x;
    const int wv   = tid >> 6;
    const int lane = tid & 63;
    const int lc   = lane & 15;
    const int lr   = lane >> 4;
    const int m0   = blockIdx.x * 64;
    const int n0w  = wv * 64;

    f32x4 acc[4][4];
#pragma unroll
    for (int i = 0; i < 4; i++)
#pragma unroll
        for (int j = 0; j < 4; j++) {
            acc[i][j][0] = 0.f; acc[i][j][1] = 0.f;
            acc[i][j][2] = 0.f; acc[i][j][3] = 0.f;
        }

    const int srow = tid >> 2;
    const int sseg = tid & 3;
    const bool inb = (m0 + srow) < M;

    for (int k0 = 0; k0 < 512; k0 += 64) {
        float4 av0, av1, av2, av3;
        if (inb) {
            const float4* ap = (const float4*)(A + (size_t)(m0 + srow) * 512 + k0 + sseg * 16);
            av0 = ap[0]; av1 = ap[1]; av2 = ap[2]; av3 = ap[3];
        } else {
            av0 = av1 = av2 = av3 = make_float4(0.f, 0.f, 0.f, 0.f);
        }
        if (k0) __syncthreads();
        f16x8 p0, p1;
        p0[0] = (_Float16)av0.x; p0[1] = (_Float16)av0.y;
        p0[2] = (_Float16)av0.z; p0[3] = (_Float16)av0.w;
        p0[4] = (_Float16)av1.x; p0[5] = (_Float16)av1.y;
        p0[6] = (_Float16)av1.z; p0[7] = (_Float16)av1.w;
        p1[0] = (_Float16)av2.x; p1[1] = (_Float16)av2.y;
        p1[2] = (_Float16)av2.z; p1[3] = (_Float16)av2.w;
        p1[4] = (_Float16)av3.x; p1[5] = (_Float16)av3.y;
        p1[6] = (_Float16)av3.z; p1[7] = (_Float16)av3.w;
        _Float16* wp = &As[srow][sseg * 16];
        *(f16x8*)wp = p0;
        *(f16x8*)(wp + 8) = p1;
        __syncthreads();

        f16x8 bf[2][4];
#pragma unroll
        for (int s = 0; s < 2; ++s)
#pragma unroll
            for (int nt = 0; nt < 4; ++nt)
                bf[s][nt] = *(const f16x8*)(Wh + (size_t)(n0w + nt * 16 + lc) * 512
                                            + k0 + s * 32 + lr * 8);

#pragma unroll
        for (int s = 0; s < 2; ++s) {
            f16x8 af[4];
#pragma unroll
            for (int mt = 0; mt < 4; ++mt)
                af[mt] = *(const f16x8*)&As[mt * 16 + lc][s * 32 + lr * 8];
#pragma unroll
            for (int mt = 0; mt < 4; ++mt)
#pragma unroll
                for (int nt = 0; nt < 4; ++nt)
                    acc[mt][nt] = __builtin_amdgcn_mfma_f32_16x16x32_f16(
                        af[mt], bf[s][nt], acc[mt][nt], 0, 0, 0);
        }
    }

    float bv[4];
#pragma unroll
    for (int nt = 0; nt < 4; ++nt) bv[nt] = bias[n0w + nt * 16 + lc];
#pragma unroll
    for (int mt = 0; mt < 4; ++mt)
#pragma unroll
        for (int r = 0; r < 4; ++r) {
            int m = m0 + mt * 16 + lr * 4 + r;
            if (m < M) {
                float* cp = C + (size_t)m * 256 + n0w + lc;
#pragma unroll
                for (int nt = 0; nt < 4; ++nt)
                    cp[nt * 16] = acc[mt][nt][r] + bv[nt];
            }
        }
}

// ------ row L2-normalize * 1.8; emit fp16 h16 (alpha term) + y0 = h*dinv --
__global__ __launch_bounds__(256) void normalize_kernel(
    const float* __restrict__ h, const float* __restrict__ dinv,
    __half* __restrict__ h16, __half* __restrict__ y0, int N) {
    int n = blockIdx.x;
    if (n >= N) return;
    int t = threadIdx.x;
    float v = h[(size_t)n * 256 + t];
    float ss = v * v;
#pragma unroll
    for (int off = 32; off > 0; off >>= 1) ss += __shfl_down(ss, off, 64);
    __shared__ float wsum[4];
    int w = t >> 6, lane = t & 63;
    if (lane == 0) wsum[w] = ss;
    __syncthreads();
    float tot = wsum[0] + wsum[1] + wsum[2] + wsum[3];
    float nrm = sqrtf(tot);
    float s = SCALE / fmaxf(nrm, 1e-12f);
    float hv = v * s;
    h16[(size_t)n * 256 + t] = __float2half(hv);
    y0[(size_t)n * 256 + t] = __float2half(hv * dinv[n]);
}

// ---------------- degree / CSR build (XCD-local scatter) ------------------
__global__ void init_counts(int* __restrict__ counts, int N) {
    int i = blockIdx.x * blockDim.x + threadIdx.x;
    if (i < N) counts[i] = 1;   // self-loop
}

__global__ __launch_bounds__(256) void count_xcd(
    const int* __restrict__ dst, int* __restrict__ counts, int E, int N) {
    const int b = blockIdx.x, x = b & 7, c = b >> 3;
    const int NC = gridDim.x >> 3;
    const int lo = (int)(((long long)x * N) >> 3);
    const int hi = (int)(((long long)(x + 1) * N) >> 3);
    const int csz = (((E + NC - 1) / NC) + 3) & ~3;
    const int e0 = c * csz;
    const int e1 = min(e0 + csz, E);
    const int rem = (e1 > e0) ? (e1 - e0) : 0;
    const int t = threadIdx.x;
    const int nvec = ((E & 3) == 0) ? (rem >> 2) : 0;
    for (int i = t; i < nvec; i += 256) {
        const int e = e0 + (i << 2);
        int4 d4 = *(const int4*)(dst + e);
        if (d4.x >= lo && d4.x < hi) atomicAdd(&counts[d4.x], 1);
        if (d4.y >= lo && d4.y < hi) atomicAdd(&counts[d4.y], 1);
        if (d4.z >= lo && d4.z < hi) atomicAdd(&counts[d4.z], 1);
        if (d4.w >= lo && d4.w < hi) atomicAdd(&counts[d4.w], 1);
    }
    for (int e = e0 + (nvec << 2) + t; e < e1; e += 256) {
        int d = dst[e];
        if (d >= lo && d < hi) atomicAdd(&counts[d], 1);
    }
}

__global__ void dinv_kernel(const int* __restrict__ counts, float* __restrict__ dinv, int N) {
    int i = blockIdx.x * blockDim.x + threadIdx.x;
    if (i < N) dinv[i] = rsqrtf((float)counts[i]);
}

__global__ __launch_bounds__(256) void scan_phase1(
    const int* __restrict__ counts, int* __restrict__ offsets,
    int* __restrict__ blocksums, int N) {
    __shared__ int sdata[256];
    int b = blockIdx.x;
    int base = b * 1024;
    int t = threadIdx.x;
    int v[4];
    int idx0 = base + t * 4;
    int sum = 0;
#pragma unroll
    for (int j = 0; j < 4; j++) {
        int i = idx0 + j;
        v[j] = (i < N) ? counts[i] : 0;
        sum += v[j];
    }
    sdata[t] = sum;
    __syncthreads();
    for (int off = 1; off < 256; off <<= 1) {
        int x = (t >= off) ? sdata[t - off] : 0;
        __syncthreads();
        sdata[t] += x;
        __syncthreads();
    }
    int incl = sdata[t];
    int excl = incl - sum;
    if (t == 255) blocksums[b] = incl;
    int run = excl;
#pragma unroll
    for (int j = 0; j < 4; j++) {
        int i = idx0 + j;
        if (i < N) offsets[i] = run;
        run += v[j];
    }
}

__global__ __launch_bounds__(128) void scan_phase2(int* __restrict__ blocksums, int nb) {
    __shared__ int s[128];
    int t = threadIdx.x;
    int v = (t < nb) ? blocksums[t] : 0;
    s[t] = v;
    __syncthreads();
    for (int off = 1; off < 128; off <<= 1) {
        int x = (t >= off) ? s[t - off] : 0;
        __syncthreads();
        s[t] += x;
        __syncthreads();
    }
    if (t < nb) blocksums[t] = s[t] - v;   // exclusive
}

__global__ void scan_phase3(int* __restrict__ offsets, const int* __restrict__ blocksums,
                            int* __restrict__ cursor, int N, int total) {
    int i = blockIdx.x * blockDim.x + threadIdx.x;
    if (i < N) {
        int o = offsets[i] + blocksums[i >> 10];
        offsets[i] = o;
        cursor[i] = o;
    }
    if (i == N) offsets[N] = total;
}

__global__ __launch_bounds__(256) void fill_xcd(
    const int* __restrict__ src, const int* __restrict__ dst,
    int* __restrict__ cursor, int* __restrict__ col, int E, int N) {
    const int b = blockIdx.x, x = b & 7, c = b >> 3;
    const int NC = gridDim.x >> 3;
    const int lo = (int)(((long long)x * N) >> 3);
    const int hi = (int)(((long long)(x + 1) * N) >> 3);
    const int csz = (((E + NC - 1) / NC) + 3) & ~3;
    const int e0 = c * csz;
    const int e1 = min(e0 + csz, E);
    const int rem = (e1 > e0) ? (e1 - e0) : 0;
    const int t = threadIdx.x;
    const int nvec = ((E & 3) == 0) ? (rem >> 2) : 0;
    for (int i = t; i < nvec; i += 256) {
        const int e = e0 + (i << 2);
        int4 d4 = *(const int4*)(dst + e);
        if (d4.x >= lo && d4.x < hi) { int p = atomicAdd(&cursor[d4.x], 1); col[p] = src[e]; }
        if (d4.y >= lo && d4.y < hi) { int p = atomicAdd(&cursor[d4.y], 1); col[p] = src[e + 1]; }
        if (d4.z >= lo && d4.z < hi) { int p = atomicAdd(&cursor[d4.z], 1); col[p] = src[e + 2]; }
        if (d4.w >= lo && d4.w < hi) { int p = atomicAdd(&cursor[d4.w], 1); col[p] = src[e + 3]; }
    }
    for (int e = e0 + (nvec << 2) + t; e < e1; e += 256) {
        int d = dst[e];
        if (d >= lo && d < hi) { int p = atomicAdd(&cursor[d], 1); col[p] = src[e]; }
    }
    if (c == 0) {
        for (int n = lo + t; n < hi; n += 256) {
            int p = atomicAdd(&cursor[n], 1);
            col[p] = n;
        }
    }
}

// ---------------- pull-SpMM over fp16 state: one wave per dst row ---------
__device__ __forceinline__ void acc_half4(float4& a, float2 r) {
    union { float2 f; __half2 h[2]; } u;
    u.f = r;
    float2 lo = __half22float2(u.h[0]);
    float2 hi = __half22float2(u.h[1]);
    a.x += lo.x; a.y += lo.y; a.z += hi.x; a.w += hi.y;
}

template <bool FINAL>
__global__ __launch_bounds__(256) void spmm_kernel(
    const __half* __restrict__ yin, const __half* __restrict__ h16,
    const int* __restrict__ offs, const int* __restrict__ col,
    const float* __restrict__ dinv, void* __restrict__ outp, int N) {
    int gw = blockIdx.x * 4 + (threadIdx.x >> 6);
    if (gw >= N) return;
    int lane = threadIdx.x & 63;
    int beg = offs[gw], end = offs[gw + 1];

    float4 a[8];
#pragma unroll
    for (int j = 0; j < 8; ++j) a[j] = make_float4(0.f, 0.f, 0.f, 0.f);

    int e = beg;
    // 8-deep gather pipeline: 8 independent rows in flight per wave
    for (; e + 7 < end; e += 8) {
        int s[8];
#pragma unroll
        for (int j = 0; j < 8; ++j) s[j] = col[e + j];
        float2 r[8];
#pragma unroll
        for (int j = 0; j < 8; ++j)
            r[j] = ((const float2*)(yin + (size_t)s[j] * 256))[lane];
#pragma unroll
        for (int j = 0; j < 8; ++j) acc_half4(a[j], r[j]);
    }
    for (; e + 3 < end; e += 4) {
        int s[4];
#pragma unroll
        for (int j = 0; j < 4; ++j) s[j] = col[e + j];
        float2 r[4];
#pragma unroll
        for (int j = 0; j < 4; ++j)
            r[j] = ((const float2*)(yin + (size_t)s[j] * 256))[lane];
#pragma unroll
        for (int j = 0; j < 4; ++j) acc_half4(a[j], r[j]);
    }
    for (; e < end; ++e) {
        int s0 = col[e];
        float2 r0 = ((const float2*)(yin + (size_t)s0 * 256))[lane];
        acc_half4(a[0], r0);
    }

    float dg = dinv[gw];
    float wd = BETA * dg;

    // alpha * h0 term (fp16, LLC-resident across iterations)
    float4 hh;
    {
        float2 hv2 = ((const float2*)(h16 + (size_t)gw * 256))[lane];
        union { float f; __half2 h; } ux, uy;
        ux.f = hv2.x; uy.f = hv2.y;
        float2 lo = __half22float2(ux.h);
        float2 hi = __half22float2(uy.h);
        hh.x = lo.x; hh.y = lo.y; hh.z = hi.x; hh.w = hi.y;
    }

    float4 t0, t1;
    t0.x = a[0].x + a[1].x; t0.y = a[0].y + a[1].y; t0.z = a[0].z + a[1].z; t0.w = a[0].w + a[1].w;
    t1.x = a[2].x + a[3].x; t1.y = a[2].y + a[3].y; t1.z = a[2].z + a[3].z; t1.w = a[2].w + a[3].w;
    t0.x += a[4].x + a[5].x; t0.y += a[4].y + a[5].y; t0.z += a[4].z + a[5].z; t0.w += a[4].w + a[5].w;
    t1.x += a[6].x + a[7].x; t1.y += a[6].y + a[7].y; t1.z += a[6].z + a[7].z; t1.w += a[6].w + a[7].w;

    float4 o;
    o.x = wd * (t0.x + t1.x) + ALPHA * hh.x;
    o.y = wd * (t0.y + t1.y) + ALPHA * hh.y;
    o.z = wd * (t0.z + t1.z) + ALPHA * hh.z;
    o.w = wd * (t0.w + t1.w) + ALPHA * hh.w;

    if (FINAL) {
        // true write-once output: nontemporal is correct here
        float* op = (float*)outp + (size_t)gw * 256 + lane * 4;
        __builtin_nontemporal_store(o.x, op);
        __builtin_nontemporal_store(o.y, op + 1);
        __builtin_nontemporal_store(o.z, op + 2);
        __builtin_nontemporal_store(o.w, op + 3);
    } else {
        // y = dinv[d] * z, re-read next iteration: keep cacheable
        __half2 p0 = __floats2half2_rn(o.x * dg, o.y * dg);
        __half2 p1 = __floats2half2_rn(o.z * dg, o.w * dg);
        union { float f; __half2 h; } u0, u1;
        u0.h = p0; u1.h = p1;
        float* op = (float*)((__half*)outp + (size_t)gw * 256) + lane * 2;
        op[0] = u0.f;
        op[1] = u1.f;
    }
}

extern "C" void kernel_launch(void* const* d_in, const int* in_sizes, int n_in,
                              void* d_out, int out_size, void* d_ws, size_t ws_size,
                              hipStream_t stream) {
    const float* x  = (const float*)d_in[0];
    const int* ei   = (const int*)d_in[1];
    const float* W1 = (const float*)d_in[2];
    const float* b1 = (const float*)d_in[3];
    float* out = (float*)d_out;

    const int N = in_sizes[0] / 512;           // 100000
    const int E = in_sizes[1] / 2;             // 3200000
    const int* src = ei;
    const int* dst = ei + E;
    const int NNZ = E + N;

    // workspace carve-up; h0 (fp32) region is reused as yA (fp16)
    char* w = (char*)d_ws;
    float* h0 = (float*)w;      w += (size_t)N * 256 * 4;      // fp32 GEMM out / later yA
    __half* h16 = (__half*)w;   w += (size_t)N * 256 * 2;      // alpha term
    __half* y0 = (__half*)w;    w += (size_t)N * 256 * 2;      // initial state
    __half* yB = (__half*)w;    w += (size_t)N * 256 * 2;      // ping-pong B
    _Float16* Wh = (_Float16*)w; w += (size_t)256 * 512 * 2;   // fp16 W1 (B frags)
    float* dinv = (float*)w;    w += (size_t)N * 4;
    int* counts = (int*)w;      w += (size_t)N * 4;            // reused as cursor
    int* offsets = (int*)w;     w += (size_t)(N + 64) * 4;
    int* blocksums = (int*)w;   w += 128 * 4;
    int* col = (int*)w;         w += (size_t)NNZ * 4;
    __half* yA = (__half*)h0;

    // degrees (incl self-loop) + dinv — needed by normalize
    init_counts<<<(N + 255) / 256, 256, 0, stream>>>(counts, N);
    count_xcd<<<512, 256, 0, stream>>>(dst, counts, E, N);
    dinv_kernel<<<(N + 255) / 256, 256, 0, stream>>>(counts, dinv, N);
    // linear1 (fp16 MFMA)
    convert_w<<<(256 * 512 + 255) / 256, 256, 0, stream>>>(W1, Wh);
    gemm_f16<<<(N + 63) / 64, 256, 0, stream>>>(x, Wh, b1, h0, N);
    // normalize -> h16, y0 (h0 fp32 dead after this; region becomes yA)
    normalize_kernel<<<N, 256, 0, stream>>>(h0, dinv, h16, y0, N);
    // CSR
    int nb = (N + 1023) / 1024;
    scan_phase1<<<nb, 256, 0, stream>>>(counts, offsets, blocksums, N);
    scan_phase2<<<1, 128, 0, stream>>>(blocksums, nb);
    scan_phase3<<<(N + 256) / 256, 256, 0, stream>>>(offsets, blocksums, counts, N, NNZ);
    fill_xcd<<<512, 256, 0, stream>>>(src, dst, counts, col, E, N);
    // APPNP: 9 fp16->fp16 steps + final fp16->fp32 into d_out
    int nblk = (N + 3) / 4;
    const __half* cur = y0;
    for (int it = 0; it < 9; ++it) {
        __half* nxt = (it & 1) ? yB : yA;
        spmm_kernel<false><<<nblk, 256, 0, stream>>>(cur, h16, offsets, col, dinv,
                                                     (void*)nxt, N);
        cur = nxt;
    }
    spmm_kernel<true><<<nblk, 256, 0, stream>>>(cur, h16, offsets, col, dinv,
                                                (void*)out, N);
}